// Round 5
// baseline (507.170 us; speedup 1.0000x reference)
//
#include <hip/hip_runtime.h>
#include <math.h>

// GCN 2-layer, CSR-gather formulation (no feature atomics).
// norm_e = dinv[src]*dinv[dst] factorizes: pre-scale rows at source (in the
// GEMM epilogue), gather-sum raw, post-scale at destination.
// CSR build: histogram -> scan -> atomic-offset fill, dst-range partitioned.
// R2 fix: range-partitioned fill (write windows ~1.6 MB per XCD L2).
// R3 fix: gemm1 LDS bank conflicts (pad strides, float4/b128).
// R4 fix: k_fill WRITE was still 13x amplified -- the 8x dst re-scan was
// thrashing L2 and evicting partial colidx lines. nt (nontemporal) loads on
// the edge streams keep the colidx window resident. k_deg back to 1 pass.

constexpr int N    = 100000;
constexpr int E    = 3200000;
constexpr int F_IN = 128;
constexpr int H    = 50;
constexpr int C    = 2;
constexpr int NB   = (N + 1023) / 1024;   // 98 scan blocks

constexpr int NRANGE = 8;                     // dst-space partitions (~XCDs)
constexpr int RSPAN  = (N + NRANGE - 1) / NRANGE;   // 12500 nodes/range
constexpr int NSLICE = 256;                   // edge slices per range
constexpr int ESLICE = (E + NSLICE - 1) / NSLICE;   // 12500 edges/slice

constexpr int XS_LD = F_IN + 4;   // 132: (4r+k)%32 -> worst 2-way (free)
constexpr int WS_LD = 64;         // padded j-dim, 16-aligned groups

// ---------------- CSR build ----------------

__global__ __launch_bounds__(256) void k_zero(int* __restrict__ degi) {
    int i = blockIdx.x * blockDim.x + threadIdx.x;
    if (i < N) degi[i] = 0;
}

// single-pass histogram, nt loads (histogram is 400 KB, L2/L3-resident)
__global__ __launch_bounds__(256) void k_deg(const int* __restrict__ dst,
                                             int* __restrict__ degi) {
    long stride = (long)gridDim.x * blockDim.x;
    for (long e = (long)blockIdx.x * blockDim.x + threadIdx.x; e < E; e += stride) {
        int d = __builtin_nontemporal_load(dst + e);
        atomicAdd(&degi[d], 1);
    }
}

// Pass A: per-1024-chunk totals
__global__ __launch_bounds__(256) void k_blocksum(const int* __restrict__ degi,
                                                  int* __restrict__ bsum) {
    const int t = threadIdx.x, b = blockIdx.x;
    long i0 = (long)b * 1024 + t * 4;
    int s = 0;
    #pragma unroll
    for (int u = 0; u < 4; ++u) { long i = i0 + u; if (i < N) s += degi[i]; }
    #pragma unroll
    for (int o = 32; o > 0; o >>= 1) s += __shfl_xor(s, o);
    __shared__ int ws_[4];
    int lane = t & 63, wid = t >> 6;
    if (lane == 0) ws_[wid] = s;
    __syncthreads();
    if (t == 0) bsum[b] = ws_[0] + ws_[1] + ws_[2] + ws_[3];
}

// Pass B: exclusive scan of 98 block totals (single block)
__global__ __launch_bounds__(128) void k_scanbsum(const int* __restrict__ bsum,
                                                  int* __restrict__ boff) {
    const int t = threadIdx.x;
    __shared__ int tmp[128];
    int v = (t < NB) ? bsum[t] : 0;
    tmp[t] = v;
    __syncthreads();
    for (int o = 1; o < 128; o <<= 1) {
        int y = (t >= o) ? tmp[t - o] : 0;
        __syncthreads();
        tmp[t] += y;
        __syncthreads();
    }
    if (t < NB) boff[t] = tmp[t] - v;   // exclusive
}

// Pass C: final exclusive scan -> rowptr, fillcur
__global__ __launch_bounds__(256) void k_scanfinal(const int* __restrict__ degi,
                                                   const int* __restrict__ boff,
                                                   int* __restrict__ rowptr,
                                                   int* __restrict__ fillcur) {
    const int t = threadIdx.x, b = blockIdx.x;
    const int lane = t & 63, wid = t >> 6;
    long i0 = (long)b * 1024 + t * 4;
    int d[4];
    #pragma unroll
    for (int u = 0; u < 4; ++u) { long i = i0 + u; d[u] = (i < N) ? degi[i] : 0; }
    int tsum = d[0] + d[1] + d[2] + d[3];
    int incl = tsum;
    #pragma unroll
    for (int o = 1; o < 64; o <<= 1) {
        int y = __shfl_up(incl, o);
        if (lane >= o) incl += y;
    }
    __shared__ int wsum[4];
    if (lane == 63) wsum[wid] = incl;
    __syncthreads();
    int wbase = 0;
    for (int w = 0; w < 4; ++w) if (w < wid) wbase += wsum[w];
    int base = boff[b] + wbase + (incl - tsum);
    int run = base;
    #pragma unroll
    for (int u = 0; u < 4; ++u) {
        long i = i0 + u;
        if (i < N) { rowptr[i] = run; fillcur[i] = run; }
        run += d[u];
    }
}

__global__ __launch_bounds__(256) void k_dinv(const int* __restrict__ degi,
                                              float* __restrict__ dinv) {
    int i = blockIdx.x * blockDim.x + threadIdx.x;
    if (i < N) dinv[i] = rsqrtf((float)degi[i] + 1.0f);   // +1 self loop
}

// range-partitioned fill, nt edge-stream loads: colidx window (~1.6 MB/XCD)
// stays L2-resident; lines written back once when full.
__global__ __launch_bounds__(256) void k_fill(const int* __restrict__ src,
                                              const int* __restrict__ dst,
                                              int* __restrict__ fillcur,
                                              int* __restrict__ colidx) {
    const int r  = blockIdx.x % NRANGE;
    const int s  = blockIdx.x / NRANGE;
    const int lo = r * RSPAN, hi = min(N, lo + RSPAN);
    long e0 = (long)s * ESLICE;
    long e1 = min((long)E, e0 + ESLICE);
    for (long e = e0 + threadIdx.x; e < e1; e += 256) {
        int d = __builtin_nontemporal_load(dst + e);
        if (d >= lo && d < hi) {
            int sv = __builtin_nontemporal_load(src + e);
            int pos = atomicAdd(&fillcur[d], 1);
            colidx[pos] = sv;
        }
    }
}

// ---------------- compute ----------------

// h1[i][j] = dinv[i] * sum_k x[i][k] * W1[k][j]
// 64 rows/block, 256 threads: r = t>>2 (row), g = t&3 (16-wide j group).
__global__ __launch_bounds__(256, 2) void k_gemm1(const float* __restrict__ x,
                                                  const float* __restrict__ W1,
                                                  const float* __restrict__ dinv,
                                                  float* __restrict__ h1) {
    __shared__ float xs[64][XS_LD];     // 33 KB, padded vs bank conflicts
    __shared__ float Ws[F_IN][WS_LD];   // 32 KB, j padded to 64
    const int t = threadIdx.x;
    const int row0 = blockIdx.x * 64;

    // stage W1 [128][50] -> Ws [128][64]
    for (int i = t; i < F_IN * H; i += 256)
        Ws[i / H][i % H] = W1[i];
    for (int i = t; i < F_IN * (WS_LD - H); i += 256)
        Ws[i / (WS_LD - H)][H + i % (WS_LD - H)] = 0.0f;
    // stage x rows as float4 (coalesced)
    for (int i = t; i < 64 * (F_IN / 4); i += 256) {
        int r  = i >> 5;          // /32 float4s per row
        int c4 = i & 31;
        int gr = row0 + r;
        float4 v = make_float4(0.f, 0.f, 0.f, 0.f);
        if (gr < N) v = *(const float4*)(x + (long)gr * F_IN + c4 * 4);
        *(float4*)&xs[r][c4 * 4] = v;
    }
    __syncthreads();

    const int r  = t >> 2;
    const int g  = t & 3;
    const int j0 = g * 16;
    float acc[16];
    #pragma unroll
    for (int u = 0; u < 16; ++u) acc[u] = 0.0f;

    const float* xrow = &xs[r][0];
    #pragma unroll 4
    for (int k0 = 0; k0 < F_IN; k0 += 4) {
        float4 xv = *(const float4*)(xrow + k0);
        float xk[4] = {xv.x, xv.y, xv.z, xv.w};
        #pragma unroll
        for (int kk = 0; kk < 4; ++kk) {
            const float* wrow = &Ws[k0 + kk][j0];
            float4 wa = *(const float4*)(wrow);
            float4 wb = *(const float4*)(wrow + 4);
            float4 wc = *(const float4*)(wrow + 8);
            float4 wd = *(const float4*)(wrow + 12);
            float xr = xk[kk];
            acc[0]  += xr * wa.x; acc[1]  += xr * wa.y;
            acc[2]  += xr * wa.z; acc[3]  += xr * wa.w;
            acc[4]  += xr * wb.x; acc[5]  += xr * wb.y;
            acc[6]  += xr * wb.z; acc[7]  += xr * wb.w;
            acc[8]  += xr * wc.x; acc[9]  += xr * wc.y;
            acc[10] += xr * wc.z; acc[11] += xr * wc.w;
            acc[12] += xr * wd.x; acc[13] += xr * wd.y;
            acc[14] += xr * wd.z; acc[15] += xr * wd.w;
        }
    }

    int gr = row0 + r;
    if (gr >= N) return;
    float di = dinv[gr];
    #pragma unroll
    for (int u = 0; u < 16; ++u) {
        int j = j0 + u;
        if (j < H) h1[(long)gr * H + j] = di * acc[u];
    }
}

// wave-per-node: agg1 = self + sum_{nbr} h1[nbr]; z1 = relu(di*agg1+b1);
// h2[i] = di * (z1 @ W2)
__global__ __launch_bounds__(256) void k_agg1_fused(const int* __restrict__ rowptr,
                                                    const int* __restrict__ degi,
                                                    const int* __restrict__ colidx,
                                                    const float* __restrict__ h1,
                                                    const float* __restrict__ dinv,
                                                    const float* __restrict__ b1,
                                                    const float* __restrict__ W2,
                                                    float* __restrict__ h2) {
    const int lane = threadIdx.x & 63;
    const bool act = lane < H;
    float b1v = act ? b1[lane] : 0.0f;
    float w20 = act ? W2[lane * 2 + 0] : 0.0f;
    float w21 = act ? W2[lane * 2 + 1] : 0.0f;

    long gw = ((long)blockIdx.x * blockDim.x + threadIdx.x) >> 6;
    long nw = ((long)gridDim.x * blockDim.x) >> 6;
    for (long i = gw; i < N; i += nw) {
        const int start = rowptr[i];
        const int deg   = degi[i];
        float a0 = act ? h1[i * (long)H + lane] : 0.0f;   // self loop
        float a1 = 0.0f, a2 = 0.0f, a3 = 0.0f;
        int k = 0;
        for (; k + 4 <= deg; k += 4) {
            int s0 = colidx[start + k + 0];
            int s1 = colidx[start + k + 1];
            int s2 = colidx[start + k + 2];
            int s3 = colidx[start + k + 3];
            if (act) {
                a0 += h1[(long)s0 * H + lane];
                a1 += h1[(long)s1 * H + lane];
                a2 += h1[(long)s2 * H + lane];
                a3 += h1[(long)s3 * H + lane];
            }
        }
        for (; k < deg; ++k) {
            int s = colidx[start + k];
            if (act) a0 += h1[(long)s * H + lane];
        }
        float agg = (a0 + a1) + (a2 + a3);
        float di = dinv[i];
        float v = fmaxf(di * agg + b1v, 0.0f);
        float p0 = v * w20, p1 = v * w21;
        #pragma unroll
        for (int o = 32; o > 0; o >>= 1) {
            p0 += __shfl_xor(p0, o);
            p1 += __shfl_xor(p1, o);
        }
        if (lane == 0) {
            h2[i * 2 + 0] = di * p0;
            h2[i * 2 + 1] = di * p1;
        }
    }
}

// wave-per-node, lanes over edges: out = log_softmax(di*(sum+self)+b2)
__global__ __launch_bounds__(256) void k_agg2_final(const int* __restrict__ rowptr,
                                                    const int* __restrict__ degi,
                                                    const int* __restrict__ colidx,
                                                    const float* __restrict__ h2,
                                                    const float* __restrict__ dinv,
                                                    const float* __restrict__ b2,
                                                    float* __restrict__ out) {
    const int lane = threadIdx.x & 63;
    long gw = ((long)blockIdx.x * blockDim.x + threadIdx.x) >> 6;
    long nw = ((long)gridDim.x * blockDim.x) >> 6;
    for (long i = gw; i < N; i += nw) {
        const int start = rowptr[i];
        const int deg   = degi[i];
        float s0 = 0.0f, s1 = 0.0f;
        for (int k = lane; k < deg; k += 64) {
            int s = colidx[start + k];
            s0 += h2[(long)s * 2 + 0];
            s1 += h2[(long)s * 2 + 1];
        }
        #pragma unroll
        for (int o = 32; o > 0; o >>= 1) {
            s0 += __shfl_xor(s0, o);
            s1 += __shfl_xor(s1, o);
        }
        if (lane == 0) {
            float di = dinv[i];
            float a0 = di * (s0 + h2[i * 2 + 0]) + b2[0];
            float a1 = di * (s1 + h2[i * 2 + 1]) + b2[1];
            float m = fmaxf(a0, a1);
            float lse = m + logf(expf(a0 - m) + expf(a1 - m));
            out[i * 2 + 0] = a0 - lse;
            out[i * 2 + 1] = a1 - lse;
        }
    }
}

extern "C" void kernel_launch(void* const* d_in, const int* in_sizes, int n_in,
                              void* d_out, int out_size, void* d_ws, size_t ws_size,
                              hipStream_t stream) {
    const float* x  = (const float*)d_in[0];
    const int*   ei = (const int*)d_in[1];   // [2][E]: row0 src, row1 dst
    const float* W1 = (const float*)d_in[2];
    const float* b1 = (const float*)d_in[3];
    const float* W2 = (const float*)d_in[4];
    const float* b2 = (const float*)d_in[5];
    float* out = (float*)d_out;

    const int* src = ei;
    const int* dst = ei + E;

    // ws layout
    int*   degi    = (int*)d_ws;            // N
    int*   rowptr  = degi + N;              // N
    int*   fillcur = rowptr + N;            // N
    int*   bsum    = fillcur + N;           // 128
    int*   boff    = bsum + 128;            // 128
    float* dinv    = (float*)(boff + 128);  // N
    int*   colidx  = (int*)(dinv + N);      // E
    float* h1      = (float*)(colidx + E);  // N*H
    float* h2      = h1 + (long)N * H;      // N*C   (~35 MB total)

    k_zero<<<(N + 255) / 256, 256, 0, stream>>>(degi);
    k_deg<<<2048, 256, 0, stream>>>(dst, degi);
    k_blocksum<<<NB, 256, 0, stream>>>(degi, bsum);
    k_scanbsum<<<1, 128, 0, stream>>>(bsum, boff);
    k_scanfinal<<<NB, 256, 0, stream>>>(degi, boff, rowptr, fillcur);
    k_dinv<<<(N + 255) / 256, 256, 0, stream>>>(degi, dinv);
    k_fill<<<NRANGE * NSLICE, 256, 0, stream>>>(src, dst, fillcur, colidx);
    k_gemm1<<<(N + 63) / 64, 256, 0, stream>>>(x, W1, dinv, h1);
    k_agg1_fused<<<2048, 256, 0, stream>>>(rowptr, degi, colidx, h1, dinv, b1, W2, h2);
    k_agg2_final<<<2048, 256, 0, stream>>>(rowptr, degi, colidx, h2, dinv, b2, out);
}

// Round 7
// 473.971 us; speedup vs baseline: 1.0700x; 1.0700x over previous
//
#include <hip/hip_runtime.h>
#include <hip/hip_fp16.h>
#include <math.h>

// GCN 2-layer, CSR-gather formulation (no feature atomics).
// norm_e = dinv[src]*dinv[dst] factorizes: pre-scale rows at source (in the
// GEMM epilogue), gather-sum raw, post-scale at destination.
// R2: range-partitioned fill. R3: gemm1 LDS bank-conflict fix.
// R5: (a) fill/deg are latency-bound (VALUBusy 4%) -> int4 edge loads, 4
// independent chains/thread, src always-loaded coalesced. (b) h1 stored fp16,
// rows padded to 64 (128 B = exactly 2 cache lines per gather).
// R6: __builtin_nontemporal_load needs a native clang vector type, not
// HIP_vector_type -> ext_vector_type(4) int.

constexpr int N    = 100000;
constexpr int E    = 3200000;
constexpr int F_IN = 128;
constexpr int H    = 50;
constexpr int C    = 2;
constexpr int HP   = 64;                  // padded h1 row (halves)
constexpr int NB   = (N + 1023) / 1024;   // 98 scan blocks

constexpr int NRANGE = 8;                     // dst-space partitions (~XCDs)
constexpr int RSPAN  = (N + NRANGE - 1) / NRANGE;   // 12500 nodes/range
constexpr int NSLICE = 256;                   // edge slices per range
constexpr int ESLICE = (E + NSLICE - 1) / NSLICE;   // 12500 edges/slice (div by 4)

constexpr int XS_LD = F_IN + 4;   // 132: (4r+k)%32 -> worst 2-way (free)
constexpr int WS_LD = 64;         // padded j-dim, 16-aligned groups

typedef int int4v __attribute__((ext_vector_type(4)));   // nt-load-compatible

// ---------------- CSR build ----------------

__global__ __launch_bounds__(256) void k_zero(int* __restrict__ degi) {
    int i = blockIdx.x * blockDim.x + threadIdx.x;
    if (i < N) degi[i] = 0;
}

// single-pass histogram, int4 loads: 4 independent atomic chains per thread
__global__ __launch_bounds__(256) void k_deg(const int* __restrict__ dst,
                                             int* __restrict__ degi) {
    const int4v* dst4 = (const int4v*)dst;
    long nq = E / 4;
    long stride = (long)gridDim.x * blockDim.x;
    for (long q = (long)blockIdx.x * blockDim.x + threadIdx.x; q < nq; q += stride) {
        int4v d4 = __builtin_nontemporal_load(dst4 + q);
        atomicAdd(&degi[d4.x], 1);
        atomicAdd(&degi[d4.y], 1);
        atomicAdd(&degi[d4.z], 1);
        atomicAdd(&degi[d4.w], 1);
    }
}

// Pass A: per-1024-chunk totals
__global__ __launch_bounds__(256) void k_blocksum(const int* __restrict__ degi,
                                                  int* __restrict__ bsum) {
    const int t = threadIdx.x, b = blockIdx.x;
    long i0 = (long)b * 1024 + t * 4;
    int s = 0;
    #pragma unroll
    for (int u = 0; u < 4; ++u) { long i = i0 + u; if (i < N) s += degi[i]; }
    #pragma unroll
    for (int o = 32; o > 0; o >>= 1) s += __shfl_xor(s, o);
    __shared__ int ws_[4];
    int lane = t & 63, wid = t >> 6;
    if (lane == 0) ws_[wid] = s;
    __syncthreads();
    if (t == 0) bsum[b] = ws_[0] + ws_[1] + ws_[2] + ws_[3];
}

// Pass B: exclusive scan of 98 block totals (single block)
__global__ __launch_bounds__(128) void k_scanbsum(const int* __restrict__ bsum,
                                                  int* __restrict__ boff) {
    const int t = threadIdx.x;
    __shared__ int tmp[128];
    int v = (t < NB) ? bsum[t] : 0;
    tmp[t] = v;
    __syncthreads();
    for (int o = 1; o < 128; o <<= 1) {
        int y = (t >= o) ? tmp[t - o] : 0;
        __syncthreads();
        tmp[t] += y;
        __syncthreads();
    }
    if (t < NB) boff[t] = tmp[t] - v;   // exclusive
}

// Pass C: final exclusive scan -> rowptr, fillcur
__global__ __launch_bounds__(256) void k_scanfinal(const int* __restrict__ degi,
                                                   const int* __restrict__ boff,
                                                   int* __restrict__ rowptr,
                                                   int* __restrict__ fillcur) {
    const int t = threadIdx.x, b = blockIdx.x;
    const int lane = t & 63, wid = t >> 6;
    long i0 = (long)b * 1024 + t * 4;
    int d[4];
    #pragma unroll
    for (int u = 0; u < 4; ++u) { long i = i0 + u; d[u] = (i < N) ? degi[i] : 0; }
    int tsum = d[0] + d[1] + d[2] + d[3];
    int incl = tsum;
    #pragma unroll
    for (int o = 1; o < 64; o <<= 1) {
        int y = __shfl_up(incl, o);
        if (lane >= o) incl += y;
    }
    __shared__ int wsum[4];
    if (lane == 63) wsum[wid] = incl;
    __syncthreads();
    int wbase = 0;
    for (int w = 0; w < 4; ++w) if (w < wid) wbase += wsum[w];
    int base = boff[b] + wbase + (incl - tsum);
    int run = base;
    #pragma unroll
    for (int u = 0; u < 4; ++u) {
        long i = i0 + u;
        if (i < N) { rowptr[i] = run; fillcur[i] = run; }
        run += d[u];
    }
}

__global__ __launch_bounds__(256) void k_dinv(const int* __restrict__ degi,
                                              float* __restrict__ dinv) {
    int i = blockIdx.x * blockDim.x + threadIdx.x;
    if (i < N) dinv[i] = rsqrtf((float)degi[i] + 1.0f);   // +1 self loop
}

// range-partitioned fill, int4 coalesced dst+src loads, 4 chains/thread
__global__ __launch_bounds__(256) void k_fill(const int* __restrict__ src,
                                              const int* __restrict__ dst,
                                              int* __restrict__ fillcur,
                                              int* __restrict__ colidx) {
    const int r  = blockIdx.x % NRANGE;
    const int s  = blockIdx.x / NRANGE;
    const int lo = r * RSPAN, hi = min(N, lo + RSPAN);
    const int4v* dst4 = (const int4v*)dst;
    const int4v* src4 = (const int4v*)src;
    long q0 = (long)s * (ESLICE / 4);
    long q1 = q0 + ESLICE / 4;
    long qmax = E / 4;
    if (q1 > qmax) q1 = qmax;
    for (long q = q0 + threadIdx.x; q < q1; q += 256) {
        int4v d4 = __builtin_nontemporal_load(dst4 + q);
        int4v s4 = __builtin_nontemporal_load(src4 + q);
        if (d4.x >= lo && d4.x < hi) { int p = atomicAdd(&fillcur[d4.x], 1); colidx[p] = s4.x; }
        if (d4.y >= lo && d4.y < hi) { int p = atomicAdd(&fillcur[d4.y], 1); colidx[p] = s4.y; }
        if (d4.z >= lo && d4.z < hi) { int p = atomicAdd(&fillcur[d4.z], 1); colidx[p] = s4.z; }
        if (d4.w >= lo && d4.w < hi) { int p = atomicAdd(&fillcur[d4.w], 1); colidx[p] = s4.w; }
    }
}

// ---------------- compute ----------------

// h1[i][j] = dinv[i] * sum_k x[i][k] * W1[k][j], stored fp16 padded to 64
__global__ __launch_bounds__(256, 2) void k_gemm1(const float* __restrict__ x,
                                                  const float* __restrict__ W1,
                                                  const float* __restrict__ dinv,
                                                  __half* __restrict__ h1) {
    __shared__ float xs[64][XS_LD];     // 33 KB, padded vs bank conflicts
    __shared__ float Ws[F_IN][WS_LD];   // 32 KB, j padded to 64
    const int t = threadIdx.x;
    const int row0 = blockIdx.x * 64;

    for (int i = t; i < F_IN * H; i += 256)
        Ws[i / H][i % H] = W1[i];
    for (int i = t; i < F_IN * (WS_LD - H); i += 256)
        Ws[i / (WS_LD - H)][H + i % (WS_LD - H)] = 0.0f;
    for (int i = t; i < 64 * (F_IN / 4); i += 256) {
        int r  = i >> 5;
        int c4 = i & 31;
        int gr = row0 + r;
        float4 v = make_float4(0.f, 0.f, 0.f, 0.f);
        if (gr < N) v = *(const float4*)(x + (long)gr * F_IN + c4 * 4);
        *(float4*)&xs[r][c4 * 4] = v;
    }
    __syncthreads();

    const int r  = t >> 2;
    const int g  = t & 3;
    const int j0 = g * 16;
    float acc[16];
    #pragma unroll
    for (int u = 0; u < 16; ++u) acc[u] = 0.0f;

    const float* xrow = &xs[r][0];
    #pragma unroll 4
    for (int k0 = 0; k0 < F_IN; k0 += 4) {
        float4 xv = *(const float4*)(xrow + k0);
        float xk[4] = {xv.x, xv.y, xv.z, xv.w};
        #pragma unroll
        for (int kk = 0; kk < 4; ++kk) {
            const float* wrow = &Ws[k0 + kk][j0];
            float4 wa = *(const float4*)(wrow);
            float4 wb = *(const float4*)(wrow + 4);
            float4 wc = *(const float4*)(wrow + 8);
            float4 wd = *(const float4*)(wrow + 12);
            float xr = xk[kk];
            acc[0]  += xr * wa.x; acc[1]  += xr * wa.y;
            acc[2]  += xr * wa.z; acc[3]  += xr * wa.w;
            acc[4]  += xr * wb.x; acc[5]  += xr * wb.y;
            acc[6]  += xr * wb.z; acc[7]  += xr * wb.w;
            acc[8]  += xr * wc.x; acc[9]  += xr * wc.y;
            acc[10] += xr * wc.z; acc[11] += xr * wc.w;
            acc[12] += xr * wd.x; acc[13] += xr * wd.y;
            acc[14] += xr * wd.z; acc[15] += xr * wd.w;
        }
    }

    int gr = row0 + r;
    if (gr >= N) return;
    float di = dinv[gr];
    __half* hrow = h1 + (long)gr * HP + j0;
    #pragma unroll
    for (int u = 0; u < 16; u += 2) {
        int j = j0 + u;
        if (j < H) {
            __half2 hv;
            hv.x = __float2half(di * acc[u]);
            hv.y = (j + 1 < H) ? __float2half(di * acc[u + 1]) : __half(0);
            *(__half2*)(hrow + u) = hv;
        }
    }
}

// wave-per-node: agg1 = self + sum_{nbr} h1[nbr]; z1 = relu(di*agg1+b1);
// h2[i] = di * (z1 @ W2).  h1 fp16, rows 128 B (2 lines) each.
__global__ __launch_bounds__(256) void k_agg1_fused(const int* __restrict__ rowptr,
                                                    const int* __restrict__ degi,
                                                    const int* __restrict__ colidx,
                                                    const __half* __restrict__ h1,
                                                    const float* __restrict__ dinv,
                                                    const float* __restrict__ b1,
                                                    const float* __restrict__ W2,
                                                    float* __restrict__ h2) {
    const int lane = threadIdx.x & 63;
    const bool act = lane < H;
    float b1v = act ? b1[lane] : 0.0f;
    float w20 = act ? W2[lane * 2 + 0] : 0.0f;
    float w21 = act ? W2[lane * 2 + 1] : 0.0f;

    long gw = ((long)blockIdx.x * blockDim.x + threadIdx.x) >> 6;
    long nw = ((long)gridDim.x * blockDim.x) >> 6;
    for (long i = gw; i < N; i += nw) {
        const int start = rowptr[i];
        const int deg   = degi[i];
        float a0 = act ? __half2float(h1[i * (long)HP + lane]) : 0.0f;  // self
        float a1 = 0.0f, a2 = 0.0f, a3 = 0.0f;
        int k = 0;
        for (; k + 4 <= deg; k += 4) {
            int s0 = colidx[start + k + 0];
            int s1 = colidx[start + k + 1];
            int s2 = colidx[start + k + 2];
            int s3 = colidx[start + k + 3];
            if (act) {
                a0 += __half2float(h1[(long)s0 * HP + lane]);
                a1 += __half2float(h1[(long)s1 * HP + lane]);
                a2 += __half2float(h1[(long)s2 * HP + lane]);
                a3 += __half2float(h1[(long)s3 * HP + lane]);
            }
        }
        for (; k < deg; ++k) {
            int s = colidx[start + k];
            if (act) a0 += __half2float(h1[(long)s * HP + lane]);
        }
        float agg = (a0 + a1) + (a2 + a3);
        float di = dinv[i];
        float v = fmaxf(di * agg + b1v, 0.0f);
        float p0 = v * w20, p1 = v * w21;
        #pragma unroll
        for (int o = 32; o > 0; o >>= 1) {
            p0 += __shfl_xor(p0, o);
            p1 += __shfl_xor(p1, o);
        }
        if (lane == 0) {
            h2[i * 2 + 0] = di * p0;
            h2[i * 2 + 1] = di * p1;
        }
    }
}

// wave-per-node, lanes over edges: out = log_softmax(di*(sum+self)+b2)
__global__ __launch_bounds__(256) void k_agg2_final(const int* __restrict__ rowptr,
                                                    const int* __restrict__ degi,
                                                    const int* __restrict__ colidx,
                                                    const float* __restrict__ h2,
                                                    const float* __restrict__ dinv,
                                                    const float* __restrict__ b2,
                                                    float* __restrict__ out) {
    const int lane = threadIdx.x & 63;
    long gw = ((long)blockIdx.x * blockDim.x + threadIdx.x) >> 6;
    long nw = ((long)gridDim.x * blockDim.x) >> 6;
    for (long i = gw; i < N; i += nw) {
        const int start = rowptr[i];
        const int deg   = degi[i];
        float s0 = 0.0f, s1 = 0.0f;
        for (int k = lane; k < deg; k += 64) {
            int s = colidx[start + k];
            s0 += h2[(long)s * 2 + 0];
            s1 += h2[(long)s * 2 + 1];
        }
        #pragma unroll
        for (int o = 32; o > 0; o >>= 1) {
            s0 += __shfl_xor(s0, o);
            s1 += __shfl_xor(s1, o);
        }
        if (lane == 0) {
            float di = dinv[i];
            float a0 = di * (s0 + h2[i * 2 + 0]) + b2[0];
            float a1 = di * (s1 + h2[i * 2 + 1]) + b2[1];
            float m = fmaxf(a0, a1);
            float lse = m + logf(expf(a0 - m) + expf(a1 - m));
            out[i * 2 + 0] = a0 - lse;
            out[i * 2 + 1] = a1 - lse;
        }
    }
}

extern "C" void kernel_launch(void* const* d_in, const int* in_sizes, int n_in,
                              void* d_out, int out_size, void* d_ws, size_t ws_size,
                              hipStream_t stream) {
    const float* x  = (const float*)d_in[0];
    const int*   ei = (const int*)d_in[1];   // [2][E]: row0 src, row1 dst
    const float* W1 = (const float*)d_in[2];
    const float* b1 = (const float*)d_in[3];
    const float* W2 = (const float*)d_in[4];
    const float* b2 = (const float*)d_in[5];
    float* out = (float*)d_out;

    const int* src = ei;
    const int* dst = ei + E;

    // ws layout
    int*    degi    = (int*)d_ws;            // N
    int*    rowptr  = degi + N;              // N
    int*    fillcur = rowptr + N;            // N
    int*    bsum    = fillcur + N;           // 128
    int*    boff    = bsum + 128;            // 128
    float*  dinv    = (float*)(boff + 128);  // N
    int*    colidx  = (int*)(dinv + N);      // E
    __half* h1      = (__half*)(colidx + E); // N*64 halves (12.8 MB)
    float*  h2      = (float*)(h1 + (long)N * HP);  // N*C  (~28 MB total)

    k_zero<<<(N + 255) / 256, 256, 0, stream>>>(degi);
    k_deg<<<2048, 256, 0, stream>>>(dst, degi);
    k_blocksum<<<NB, 256, 0, stream>>>(degi, bsum);
    k_scanbsum<<<1, 128, 0, stream>>>(bsum, boff);
    k_scanfinal<<<NB, 256, 0, stream>>>(degi, boff, rowptr, fillcur);
    k_dinv<<<(N + 255) / 256, 256, 0, stream>>>(degi, dinv);
    k_fill<<<NRANGE * NSLICE, 256, 0, stream>>>(src, dst, fillcur, colidx);
    k_gemm1<<<(N + 63) / 64, 256, 0, stream>>>(x, W1, dinv, h1);
    k_agg1_fused<<<2048, 256, 0, stream>>>(rowptr, degi, colidx, h1, dinv, b1, W2, h2);
    k_agg2_final<<<2048, 256, 0, stream>>>(rowptr, degi, colidx, h2, dinv, b2, out);
}